// Round 3
// baseline (647.774 us; speedup 1.0000x reference)
//
#include <hip/hip_runtime.h>
#include <hip/hip_cooperative_groups.h>

namespace cg = cooperative_groups;

#define N_NODES 10000
#define N_EDGES 640000
#define IN_DIM  128
#define HID_DIM 256
#define OUT_DIM 128

#define MAXDEG  128   // deg ~ Binom(640k,1e-4): mean 64, P(>128) ~ 1e-11

#define GRID_BLOCKS 512
#define NTHREADS (GRID_BLOCKS * 256)     // 131072
#define NWAVES   (NTHREADS / 64)         // 2048

typedef __attribute__((ext_vector_type(8))) short short8;
typedef __attribute__((ext_vector_type(4))) float float4v;
typedef unsigned short ushort_t;
typedef unsigned int uint_t;

__device__ inline ushort_t f2bf(float f) {
    uint_t u = __float_as_uint(f);
    u += 0x7fffu + ((u >> 16) & 1u);
    return (ushort_t)(u >> 16);
}
__device__ inline float bf_lo(uint_t u) { return __uint_as_float(u << 16); }
__device__ inline float bf_hi(uint_t u) { return __uint_as_float(u & 0xffff0000u); }

#define PREP_X   (N_NODES * IN_DIM)
#define PREP_W1  (HID_DIM * (2 * IN_DIM))
#define PREP_W2  (OUT_DIM * HID_DIM)
#define PREP_TOTAL (PREP_X + PREP_W1 + 2 * PREP_W2)   // 1,411,072

// ---------------------------------------------------------------------------
// Single cooperative mega-kernel. Phases separated by grid.sync() with
// explicit agent-scope fences (__threadfence) on BOTH sides: per-XCD L2s are
// non-coherent and — unlike separate dispatches — there is no launch-boundary
// cache flush inside one kernel, so the reader side must invalidate stale
// lines (incl. pre-kernel poison-fill lines) before consuming another
// phase's stores.
//   P0: prep (x->bf16, weights->transposed bf16) + atomic edge scatter
//   P1: gather-mean of x rows -> aggb
//   P2: fused GEMM layers 1+2 (LDS h-tile, projection trick) -> Pb, Rf
//   P3: gather-mean of P rows + R + b2 epilogue -> out
// ---------------------------------------------------------------------------
__global__ void __launch_bounds__(256, 2)
mega(const float* __restrict__ x, const int* __restrict__ ei,
     const float* __restrict__ W1_l, const float* __restrict__ b1,
     const float* __restrict__ W1_r, const float* __restrict__ W2_l,
     const float* __restrict__ b2, const float* __restrict__ W2_r,
     float* __restrict__ out,
     int* __restrict__ cnt, ushort_t* __restrict__ esrc2,
     ushort_t* __restrict__ xb, ushort_t* __restrict__ aggb,
     ushort_t* __restrict__ Pb,
     ushort_t* __restrict__ w1t, ushort_t* __restrict__ w2tl,
     ushort_t* __restrict__ w2tr, float* __restrict__ Rf) {
    __shared__ ushort_t hl[2][16 * 256];          // 16 KB: one 8 KB tile per 2-wave team
    cg::grid_group grid = cg::this_grid();

    const int gtid = blockIdx.x * 256 + threadIdx.x;
    const int lane = threadIdx.x & 63;

    // ================= P0: prep + scatter =================
    for (int i = gtid; i < PREP_TOTAL; i += NTHREADS) {
        if (i < PREP_X) {
            xb[i] = f2bf(x[i]);
        } else if (i < PREP_X + PREP_W1) {
            int j = i - PREP_X;
            int n = j >> 8, k = j & 255;          // w1t[n][k], n in [0,256)
            float v = (k < 128) ? W1_l[k * HID_DIM + n] : W1_r[(k - 128) * HID_DIM + n];
            w1t[j] = f2bf(v);
        } else if (i < PREP_X + PREP_W1 + PREP_W2) {
            int j = i - (PREP_X + PREP_W1);
            int n = j >> 8, k = j & 255;
            w2tl[j] = f2bf(W2_l[k * OUT_DIM + n]);
        } else {
            int j = i - (PREP_X + PREP_W1 + PREP_W2);
            int n = j >> 8, k = j & 255;
            w2tr[j] = f2bf(W2_r[k * OUT_DIM + n]);
        }
    }
    {
        const int* src = ei;
        const int* dst = ei + N_EDGES;
        for (int t = gtid; t < N_EDGES / 4; t += NTHREADS) {
            int4 s = ((const int4*)src)[t];
            int4 d = ((const int4*)dst)[t];
            int p;
            p = atomicAdd(&cnt[d.x], 1); if (p < MAXDEG) esrc2[d.x * MAXDEG + p] = (ushort_t)s.x;
            p = atomicAdd(&cnt[d.y], 1); if (p < MAXDEG) esrc2[d.y * MAXDEG + p] = (ushort_t)s.y;
            p = atomicAdd(&cnt[d.z], 1); if (p < MAXDEG) esrc2[d.z * MAXDEG + p] = (ushort_t)s.z;
            p = atomicAdd(&cnt[d.w], 1); if (p < MAXDEG) esrc2[d.w * MAXDEG + p] = (ushort_t)s.w;
        }
    }
    __threadfence(); grid.sync(); __threadfence();

    // ================= P1: gather-mean(x) -> aggb =================
    {
        const uint4* f = (const uint4*)xb;        // 16 uint4 per 256 B row
        const int g = lane >> 4;                  // slot group 0..3
        const int c = lane & 15;                  // 16 B column
        for (int n = (gtid >> 6); n < N_NODES; n += NWAVES) {
            const int deg = min(cnt[n], MAXDEG);
            const ushort_t* idx = esrc2 + n * MAXDEG;
            float a0=0,a1=0,a2=0,a3=0,a4=0,a5=0,a6=0,a7=0;
            int e = g;
            for (; e + 4 < deg; e += 8) {          // 2 rows in flight per group
                uint4 u = f[(int)idx[e] * 16 + c];
                uint4 v = f[(int)idx[e + 4] * 16 + c];
                a0 += bf_lo(u.x) + bf_lo(v.x); a1 += bf_hi(u.x) + bf_hi(v.x);
                a2 += bf_lo(u.y) + bf_lo(v.y); a3 += bf_hi(u.y) + bf_hi(v.y);
                a4 += bf_lo(u.z) + bf_lo(v.z); a5 += bf_hi(u.z) + bf_hi(v.z);
                a6 += bf_lo(u.w) + bf_lo(v.w); a7 += bf_hi(u.w) + bf_hi(v.w);
            }
            if (e < deg) {
                uint4 u = f[(int)idx[e] * 16 + c];
                a0 += bf_lo(u.x); a1 += bf_hi(u.x);
                a2 += bf_lo(u.y); a3 += bf_hi(u.y);
                a4 += bf_lo(u.z); a5 += bf_hi(u.z);
                a6 += bf_lo(u.w); a7 += bf_hi(u.w);
            }
#pragma unroll
            for (int off = 32; off >= 16; off >>= 1) {
                a0 += __shfl_down(a0, off); a1 += __shfl_down(a1, off);
                a2 += __shfl_down(a2, off); a3 += __shfl_down(a3, off);
                a4 += __shfl_down(a4, off); a5 += __shfl_down(a5, off);
                a6 += __shfl_down(a6, off); a7 += __shfl_down(a7, off);
            }
            if (g == 0) {
                const float dinv = (deg > 0) ? 1.0f / (float)deg : 0.0f;
                uint4 o;
                o.x = (uint_t)f2bf(a0 * dinv) | ((uint_t)f2bf(a1 * dinv) << 16);
                o.y = (uint_t)f2bf(a2 * dinv) | ((uint_t)f2bf(a3 * dinv) << 16);
                o.z = (uint_t)f2bf(a4 * dinv) | ((uint_t)f2bf(a5 * dinv) << 16);
                o.w = (uint_t)f2bf(a6 * dinv) | ((uint_t)f2bf(a7 * dinv) << 16);
                ((uint4*)aggb)[n * 16 + c] = o;
            }
        }
    }
    __threadfence(); grid.sync(); __threadfence();

    // ================= P2: fused GEMM layers 1+2 =================
    // team = 2 waves; wave wv computes h cols [128wv,128wv+128), stores to a
    // swizzled LDS tile; after __syncthreads, wv0 -> Pb = h@W2_l (bf16),
    // wv1 -> Rf = h@W2_r (f32). Swizzle byte ^= (row&7)<<4 (G4).
    // A-frag: A[m=lane&15][k=q*8+j]; B-frag: Wt[n][k]; C/D: col=lane&15,
    // row=q*4+reg (m89-verified layouts).
    {
        const int team = gtid >> 7;               // 0..1023; 625 used
        const int tt = (threadIdx.x >> 7) & 1;
        const int wv = (threadIdx.x >> 6) & 1;
        const int m = lane & 15, q = lane >> 4;
        const int wrow = team * 16;

        if (team < 625) {
            float4v acc[8];
#pragma unroll
            for (int t = 0; t < 8; ++t) acc[t] = (float4v){0.f, 0.f, 0.f, 0.f};
            const ushort_t* arow_a = aggb + (wrow + m) * IN_DIM + q * 8;
            const ushort_t* arow_x = xb   + (wrow + m) * IN_DIM + q * 8;
            const ushort_t* bbase1 = w1t + (wv * 128 + m) * 256 + q * 8;
#pragma unroll
            for (int s = 0; s < 8; ++s) {
                const ushort_t* ap = (s < 4) ? (arow_a + s * 32) : (arow_x + (s - 4) * 32);
                short8 a = *(const short8*)ap;
#pragma unroll
                for (int t = 0; t < 8; ++t) {
                    short8 b = *(const short8*)(bbase1 + (t * 16) * 256 + s * 32);
                    acc[t] = __builtin_amdgcn_mfma_f32_16x16x32_bf16(a, b, acc[t], 0, 0, 0);
                }
            }
#pragma unroll
            for (int t = 0; t < 8; ++t) {
                int col = wv * 128 + t * 16 + m;
                float bv = b1[col];
#pragma unroll
                for (int r = 0; r < 4; ++r) {
                    int row = q * 4 + r;
                    float v = fmaxf(acc[t][r] + bv, 0.0f);
                    int byte = (row * 512 + col * 2) ^ ((row & 7) << 4);
                    *(ushort_t*)((char*)hl[tt] + byte) = f2bf(v);
                }
            }
        }
        __syncthreads();
        if (team < 625) {
            const ushort_t* wt = wv ? w2tr : w2tl;
            float4v acc2[8];
#pragma unroll
            for (int t = 0; t < 8; ++t) acc2[t] = (float4v){0.f, 0.f, 0.f, 0.f};
            const ushort_t* bbase2 = wt + m * 256 + q * 8;
#pragma unroll
            for (int s = 0; s < 8; ++s) {
                int byte = (m * 512 + q * 16 + s * 64) ^ ((m & 7) << 4);
                short8 a = *(const short8*)((const char*)hl[tt] + byte);
#pragma unroll
                for (int t = 0; t < 8; ++t) {
                    short8 b = *(const short8*)(bbase2 + (t * 16) * 256 + s * 32);
                    acc2[t] = __builtin_amdgcn_mfma_f32_16x16x32_bf16(a, b, acc2[t], 0, 0, 0);
                }
            }
            if (wv == 0) {
#pragma unroll
                for (int t = 0; t < 8; ++t) {
                    int col = t * 16 + m;
#pragma unroll
                    for (int r = 0; r < 4; ++r)
                        Pb[(wrow + q * 4 + r) * OUT_DIM + col] = f2bf(acc2[t][r]);
                }
            } else {
#pragma unroll
                for (int t = 0; t < 8; ++t) {
                    int col = t * 16 + m;
#pragma unroll
                    for (int r = 0; r < 4; ++r)
                        Rf[(wrow + q * 4 + r) * OUT_DIM + col] = acc2[t][r];
                }
            }
        }
    }
    __threadfence(); grid.sync(); __threadfence();

    // ================= P3: gather-mean(P) + R + b2 -> out =================
    {
        const uint4* f = (const uint4*)Pb;
        const int g = lane >> 4;
        const int c = lane & 15;
        for (int n = (gtid >> 6); n < N_NODES; n += NWAVES) {
            const int deg = min(cnt[n], MAXDEG);
            const ushort_t* idx = esrc2 + n * MAXDEG;
            float a0=0,a1=0,a2=0,a3=0,a4=0,a5=0,a6=0,a7=0;
            int e = g;
            for (; e + 4 < deg; e += 8) {
                uint4 u = f[(int)idx[e] * 16 + c];
                uint4 v = f[(int)idx[e + 4] * 16 + c];
                a0 += bf_lo(u.x) + bf_lo(v.x); a1 += bf_hi(u.x) + bf_hi(v.x);
                a2 += bf_lo(u.y) + bf_lo(v.y); a3 += bf_hi(u.y) + bf_hi(v.y);
                a4 += bf_lo(u.z) + bf_lo(v.z); a5 += bf_hi(u.z) + bf_hi(v.z);
                a6 += bf_lo(u.w) + bf_lo(v.w); a7 += bf_hi(u.w) + bf_hi(v.w);
            }
            if (e < deg) {
                uint4 u = f[(int)idx[e] * 16 + c];
                a0 += bf_lo(u.x); a1 += bf_hi(u.x);
                a2 += bf_lo(u.y); a3 += bf_hi(u.y);
                a4 += bf_lo(u.z); a5 += bf_hi(u.z);
                a6 += bf_lo(u.w); a7 += bf_hi(u.w);
            }
#pragma unroll
            for (int off = 32; off >= 16; off >>= 1) {
                a0 += __shfl_down(a0, off); a1 += __shfl_down(a1, off);
                a2 += __shfl_down(a2, off); a3 += __shfl_down(a3, off);
                a4 += __shfl_down(a4, off); a5 += __shfl_down(a5, off);
                a6 += __shfl_down(a6, off); a7 += __shfl_down(a7, off);
            }
            if (g == 0) {
                const float dinv = (deg > 0) ? 1.0f / (float)deg : 0.0f;
                const int base = n * OUT_DIM + c * 8;
                float4 r0 = *(const float4*)(Rf + base);
                float4 r1 = *(const float4*)(Rf + base + 4);
                float4 o0, o1;
                o0.x = a0 * dinv + r0.x + b2[c * 8 + 0];
                o0.y = a1 * dinv + r0.y + b2[c * 8 + 1];
                o0.z = a2 * dinv + r0.z + b2[c * 8 + 2];
                o0.w = a3 * dinv + r0.w + b2[c * 8 + 3];
                o1.x = a4 * dinv + r1.x + b2[c * 8 + 4];
                o1.y = a5 * dinv + r1.y + b2[c * 8 + 5];
                o1.z = a6 * dinv + r1.z + b2[c * 8 + 6];
                o1.w = a7 * dinv + r1.w + b2[c * 8 + 7];
                *(float4*)(out + base)     = o0;
                *(float4*)(out + base + 4) = o1;
            }
        }
    }
}

// ---------------------------------------------------------------------------
// Launch: one memset node (zero atomic cursors) + one cooperative kernel.
// ---------------------------------------------------------------------------
extern "C" void kernel_launch(void* const* d_in, const int* in_sizes, int n_in,
                              void* d_out, int out_size, void* d_ws, size_t ws_size,
                              hipStream_t stream) {
    const float* x    = (const float*)d_in[0];
    const int*   ei   = (const int*)  d_in[1];
    const float* W1_l = (const float*)d_in[2];
    const float* b1   = (const float*)d_in[3];
    const float* W1_r = (const float*)d_in[4];
    const float* W2_l = (const float*)d_in[5];
    const float* b2   = (const float*)d_in[6];
    const float* W2_r = (const float*)d_in[7];
    float* out = (float*)d_out;

    // ---- workspace layout (byte offsets, all 16 B-aligned) ----
    char* w = (char*)d_ws;
    int*      cnt   = (int*)     (w + 0);          //    40,000 B (reserve 64 KB)
    ushort_t* esrc2 = (ushort_t*)(w + 65536);      // 2,560,000 B
    ushort_t* xb    = (ushort_t*)(w + 2625536);    // 2,560,000 B
    ushort_t* aggb  = (ushort_t*)(w + 5185536);    // 2,560,000 B
    ushort_t* Pb    = (ushort_t*)(w + 7745536);    // 2,560,000 B (un-aliased from aggb)
    ushort_t* w1t   = (ushort_t*)(w + 10305536);   //   131,072 B
    ushort_t* w2tl  = (ushort_t*)(w + 10436608);   //    65,536 B
    ushort_t* w2tr  = (ushort_t*)(w + 10502144);   //    65,536 B
    float*    Rf    = (float*)   (w + 10567680);   // 5,120,000 B -> ends 15,687,680

    hipMemsetAsync(cnt, 0, N_NODES * sizeof(int), stream);

    void* kargs[] = {
        (void*)&x, (void*)&ei, (void*)&W1_l, (void*)&b1, (void*)&W1_r,
        (void*)&W2_l, (void*)&b2, (void*)&W2_r, (void*)&out,
        (void*)&cnt, (void*)&esrc2, (void*)&xb, (void*)&aggb, (void*)&Pb,
        (void*)&w1t, (void*)&w2tl, (void*)&w2tr, (void*)&Rf
    };
    hipLaunchCooperativeKernel((const void*)mega, dim3(GRID_BLOCKS), dim3(256),
                               kargs, 0, stream);
}

// Round 4
// 172.869 us; speedup vs baseline: 3.7472x; 3.7472x over previous
//
#include <hip/hip_runtime.h>

#define N_NODES 10000
#define N_EDGES 640000
#define IN_DIM  128
#define HID_DIM 256
#define OUT_DIM 128

#define MAXDEG  128   // deg ~ Binom(640k,1e-4): mean 64, P(>128) ~ 1e-11

typedef __attribute__((ext_vector_type(8))) short short8;
typedef __attribute__((ext_vector_type(4))) float float4v;
typedef unsigned short ushort_t;
typedef unsigned int uint_t;

__device__ inline ushort_t f2bf(float f) {
    uint_t u = __float_as_uint(f);
    u += 0x7fffu + ((u >> 16) & 1u);
    return (ushort_t)(u >> 16);
}
__device__ inline float bf_lo(uint_t u) { return __uint_as_float(u << 16); }
__device__ inline float bf_hi(uint_t u) { return __uint_as_float(u & 0xffff0000u); }

#define PREP_X   (N_NODES * IN_DIM)
#define PREP_W1  (HID_DIM * (2 * IN_DIM))
#define PREP_W2  (OUT_DIM * HID_DIM)
#define PREP_TOTAL (PREP_X + PREP_W1 + 2 * PREP_W2)   // 1,411,072

#define NB1 1024
#define NT1 (NB1 * 256)

// ---------------------------------------------------------------------------
// K1: prep (x->bf16, weights->transposed bf16) + atomic edge scatter.
// Independent work items, grid-stride. cnt zeroed by a prior memset node
// (cannot zero in-kernel: no ordering between zeroing and scatter blocks).
// ---------------------------------------------------------------------------
__global__ void prep_scatter(const float* __restrict__ x, const int* __restrict__ ei,
                             const float* __restrict__ W1_l, const float* __restrict__ W1_r,
                             const float* __restrict__ W2_l, const float* __restrict__ W2_r,
                             ushort_t* __restrict__ xb,  ushort_t* __restrict__ w1t,
                             ushort_t* __restrict__ w2tl, ushort_t* __restrict__ w2tr,
                             int* __restrict__ cnt, ushort_t* __restrict__ esrc2) {
    const int gtid = blockIdx.x * 256 + threadIdx.x;
    for (int i = gtid; i < PREP_TOTAL; i += NT1) {
        if (i < PREP_X) {
            xb[i] = f2bf(x[i]);
        } else if (i < PREP_X + PREP_W1) {
            int j = i - PREP_X;
            int n = j >> 8, k = j & 255;          // w1t[n][k], n in [0,256)
            float v = (k < 128) ? W1_l[k * HID_DIM + n] : W1_r[(k - 128) * HID_DIM + n];
            w1t[j] = f2bf(v);
        } else if (i < PREP_X + PREP_W1 + PREP_W2) {
            int j = i - (PREP_X + PREP_W1);
            int n = j >> 8, k = j & 255;
            w2tl[j] = f2bf(W2_l[k * OUT_DIM + n]);
        } else {
            int j = i - (PREP_X + PREP_W1 + PREP_W2);
            int n = j >> 8, k = j & 255;
            w2tr[j] = f2bf(W2_r[k * OUT_DIM + n]);
        }
    }
    const int* src = ei;
    const int* dst = ei + N_EDGES;
    for (int t = gtid; t < N_EDGES / 4; t += NT1) {
        int4 s = ((const int4*)src)[t];
        int4 d = ((const int4*)dst)[t];
        int p;
        p = atomicAdd(&cnt[d.x], 1); if (p < MAXDEG) esrc2[d.x * MAXDEG + p] = (ushort_t)s.x;
        p = atomicAdd(&cnt[d.y], 1); if (p < MAXDEG) esrc2[d.y * MAXDEG + p] = (ushort_t)s.y;
        p = atomicAdd(&cnt[d.z], 1); if (p < MAXDEG) esrc2[d.z * MAXDEG + p] = (ushort_t)s.z;
        p = atomicAdd(&cnt[d.w], 1); if (p < MAXDEG) esrc2[d.w * MAXDEG + p] = (ushort_t)s.w;
    }
}

// ---------------------------------------------------------------------------
// K2: fused gather-mean + GEMM layers 1+2 per 16-node tile. 625 blocks x 512.
//   gather: wave w gathers nodes wrow+2w, wrow+2w+1 into swizzled LDS aggl
//           (agg never touches global memory).
//   phase 1: wave w computes h cols [32w,32w+32) = relu([agg|x]@W1+b1) ->
//            swizzled LDS hl.
//   phase 2: waves 0-3 -> Pb = h@W2_l (bf16, 32 cols each);
//            waves 4-7 -> Rf = h@W2_r (f32, 32 cols each).
// Swizzles (G4): aggl byte ^= ((row&7)<<4) on 256 B rows; hl byte ^=
// ((row&7)<<4) on 512 B rows. Same involution on write and read.
// A-frag: A[m=lane&15][k=q*8+j]; B-frag: Wt[n][k]; C/D: col=lane&15,
// row=q*4+reg (m89-verified layouts).
// ---------------------------------------------------------------------------
__global__ void __launch_bounds__(512)
gather_gemm(const ushort_t* __restrict__ xb, const int* __restrict__ cnt,
            const ushort_t* __restrict__ esrc2, const ushort_t* __restrict__ w1t,
            const float* __restrict__ b1, const ushort_t* __restrict__ w2tl,
            const ushort_t* __restrict__ w2tr,
            ushort_t* __restrict__ Pb, float* __restrict__ Rf) {
    __shared__ ushort_t aggl[16 * 128];           // 4 KB, swizzled
    __shared__ ushort_t hl[16 * 256];             // 8 KB, swizzled
    const int wrow = blockIdx.x * 16;
    const int w = threadIdx.x >> 6;               // wave 0..7
    const int lane = threadIdx.x & 63;

    // ---- gather 2 nodes per wave into aggl ----
    {
        const uint4* f = (const uint4*)xb;        // 16 uint4 per 256 B row
        const int g = lane >> 4;                  // slot group 0..3
        const int c = lane & 15;                  // 16 B column
        for (int i = 0; i < 2; ++i) {
            const int row = w * 2 + i;
            const int n = wrow + row;
            const int deg = min(cnt[n], MAXDEG);
            const ushort_t* idx = esrc2 + n * MAXDEG;
            float a0=0,a1=0,a2=0,a3=0,a4=0,a5=0,a6=0,a7=0;
            int e = g;
            for (; e + 4 < deg; e += 8) {          // 8 rows in flight per wave
                uint4 u = f[(int)idx[e] * 16 + c];
                uint4 v = f[(int)idx[e + 4] * 16 + c];
                a0 += bf_lo(u.x) + bf_lo(v.x); a1 += bf_hi(u.x) + bf_hi(v.x);
                a2 += bf_lo(u.y) + bf_lo(v.y); a3 += bf_hi(u.y) + bf_hi(v.y);
                a4 += bf_lo(u.z) + bf_lo(v.z); a5 += bf_hi(u.z) + bf_hi(v.z);
                a6 += bf_lo(u.w) + bf_lo(v.w); a7 += bf_hi(u.w) + bf_hi(v.w);
            }
            if (e < deg) {
                uint4 u = f[(int)idx[e] * 16 + c];
                a0 += bf_lo(u.x); a1 += bf_hi(u.x);
                a2 += bf_lo(u.y); a3 += bf_hi(u.y);
                a4 += bf_lo(u.z); a5 += bf_hi(u.z);
                a6 += bf_lo(u.w); a7 += bf_hi(u.w);
            }
#pragma unroll
            for (int off = 32; off >= 16; off >>= 1) {
                a0 += __shfl_down(a0, off); a1 += __shfl_down(a1, off);
                a2 += __shfl_down(a2, off); a3 += __shfl_down(a3, off);
                a4 += __shfl_down(a4, off); a5 += __shfl_down(a5, off);
                a6 += __shfl_down(a6, off); a7 += __shfl_down(a7, off);
            }
            if (g == 0) {
                const float dinv = (deg > 0) ? 1.0f / (float)deg : 0.0f;
                uint4 o;
                o.x = (uint_t)f2bf(a0 * dinv) | ((uint_t)f2bf(a1 * dinv) << 16);
                o.y = (uint_t)f2bf(a2 * dinv) | ((uint_t)f2bf(a3 * dinv) << 16);
                o.z = (uint_t)f2bf(a4 * dinv) | ((uint_t)f2bf(a5 * dinv) << 16);
                o.w = (uint_t)f2bf(a6 * dinv) | ((uint_t)f2bf(a7 * dinv) << 16);
                int byte = (row * 256 + c * 16) ^ ((row & 7) << 4);
                *(uint4*)((char*)aggl + byte) = o;
            }
        }
    }
    __syncthreads();

    // ---- phase 1: h cols [32w, 32w+32) ----
    const int m = lane & 15, q = lane >> 4;
    {
        float4v acc[2];
#pragma unroll
        for (int t = 0; t < 2; ++t) acc[t] = (float4v){0.f, 0.f, 0.f, 0.f};
        const ushort_t* arow_x = xb + (wrow + m) * IN_DIM + q * 8;
        const ushort_t* bbase1 = w1t + (w * 32 + m) * 256 + q * 8;
#pragma unroll
        for (int s = 0; s < 8; ++s) {
            short8 a;
            if (s < 4) {
                int byte = (m * 256 + q * 16 + s * 64) ^ ((m & 7) << 4);
                a = *(const short8*)((const char*)aggl + byte);
            } else {
                a = *(const short8*)(arow_x + (s - 4) * 32);
            }
#pragma unroll
            for (int t = 0; t < 2; ++t) {
                short8 b = *(const short8*)(bbase1 + (t * 16) * 256 + s * 32);
                acc[t] = __builtin_amdgcn_mfma_f32_16x16x32_bf16(a, b, acc[t], 0, 0, 0);
            }
        }
#pragma unroll
        for (int t = 0; t < 2; ++t) {
            int col = w * 32 + t * 16 + m;
            float bv = b1[col];
#pragma unroll
            for (int r = 0; r < 4; ++r) {
                int row = q * 4 + r;
                float v = fmaxf(acc[t][r] + bv, 0.0f);
                int byte = (row * 512 + col * 2) ^ ((row & 7) << 4);
                *(ushort_t*)((char*)hl + byte) = f2bf(v);
            }
        }
    }
    __syncthreads();

    // ---- phase 2: waves 0-3 -> P, waves 4-7 -> R ----
    {
        const int isP = (w < 4);
        const int cb = (w & 3) * 32;
        const ushort_t* wt = isP ? w2tl : w2tr;
        float4v acc2[2];
#pragma unroll
        for (int t = 0; t < 2; ++t) acc2[t] = (float4v){0.f, 0.f, 0.f, 0.f};
        const ushort_t* bbase2 = wt + (cb + m) * 256 + q * 8;
#pragma unroll
        for (int s = 0; s < 8; ++s) {
            int byte = (m * 512 + q * 16 + s * 64) ^ ((m & 7) << 4);
            short8 a = *(const short8*)((const char*)hl + byte);
#pragma unroll
            for (int t = 0; t < 2; ++t) {
                short8 b = *(const short8*)(bbase2 + (t * 16) * 256 + s * 32);
                acc2[t] = __builtin_amdgcn_mfma_f32_16x16x32_bf16(a, b, acc2[t], 0, 0, 0);
            }
        }
        if (isP) {
#pragma unroll
            for (int t = 0; t < 2; ++t) {
                int col = cb + t * 16 + m;
#pragma unroll
                for (int r = 0; r < 4; ++r)
                    Pb[(wrow + q * 4 + r) * OUT_DIM + col] = f2bf(acc2[t][r]);
            }
        } else {
#pragma unroll
            for (int t = 0; t < 2; ++t) {
                int col = cb + t * 16 + m;
#pragma unroll
                for (int r = 0; r < 4; ++r)
                    Rf[(wrow + q * 4 + r) * OUT_DIM + col] = acc2[t][r];
            }
        }
    }
}

// ---------------------------------------------------------------------------
// K3: final gather + epilogue: out[n][:] = mean_e P[esrc[e]][:] + R[n][:] + b2
// One 64-thread block per node (max TLP for the latency-bound gather).
// ---------------------------------------------------------------------------
__global__ void gather_final(const ushort_t* __restrict__ Pb,
                             const int* __restrict__ degp,
                             const ushort_t* __restrict__ esrc2,
                             const float* __restrict__ Rf,
                             const float* __restrict__ b2,
                             float* __restrict__ out) {
    const uint4* f = (const uint4*)Pb;            // 16 uint4 per row
    const int n = blockIdx.x;
    const int g = threadIdx.x >> 4;
    const int c = threadIdx.x & 15;
    const int deg = min(degp[n], MAXDEG);
    const ushort_t* idx = esrc2 + n * MAXDEG;

    float a0=0,a1=0,a2=0,a3=0,a4=0,a5=0,a6=0,a7=0;
    int e = g;
    for (; e + 4 < deg; e += 8) {
        uint4 u = f[(int)idx[e] * 16 + c];
        uint4 v = f[(int)idx[e + 4] * 16 + c];
        a0 += bf_lo(u.x) + bf_lo(v.x); a1 += bf_hi(u.x) + bf_hi(v.x);
        a2 += bf_lo(u.y) + bf_lo(v.y); a3 += bf_hi(u.y) + bf_hi(v.y);
        a4 += bf_lo(u.z) + bf_lo(v.z); a5 += bf_hi(u.z) + bf_hi(v.z);
        a6 += bf_lo(u.w) + bf_lo(v.w); a7 += bf_hi(u.w) + bf_hi(v.w);
    }
    if (e < deg) {
        uint4 u = f[(int)idx[e] * 16 + c];
        a0 += bf_lo(u.x); a1 += bf_hi(u.x);
        a2 += bf_lo(u.y); a3 += bf_hi(u.y);
        a4 += bf_lo(u.z); a5 += bf_hi(u.z);
        a6 += bf_lo(u.w); a7 += bf_hi(u.w);
    }
#pragma unroll
    for (int off = 32; off >= 16; off >>= 1) {
        a0 += __shfl_down(a0, off); a1 += __shfl_down(a1, off);
        a2 += __shfl_down(a2, off); a3 += __shfl_down(a3, off);
        a4 += __shfl_down(a4, off); a5 += __shfl_down(a5, off);
        a6 += __shfl_down(a6, off); a7 += __shfl_down(a7, off);
    }
    if (g == 0) {
        const float dinv = (deg > 0) ? 1.0f / (float)deg : 0.0f;
        const int base = n * OUT_DIM + c * 8;
        float4 r0 = *(const float4*)(Rf + base);
        float4 r1 = *(const float4*)(Rf + base + 4);
        float4 o0, o1;
        o0.x = a0 * dinv + r0.x + b2[c * 8 + 0];
        o0.y = a1 * dinv + r0.y + b2[c * 8 + 1];
        o0.z = a2 * dinv + r0.z + b2[c * 8 + 2];
        o0.w = a3 * dinv + r0.w + b2[c * 8 + 3];
        o1.x = a4 * dinv + r1.x + b2[c * 8 + 4];
        o1.y = a5 * dinv + r1.y + b2[c * 8 + 5];
        o1.z = a6 * dinv + r1.z + b2[c * 8 + 6];
        o1.w = a7 * dinv + r1.w + b2[c * 8 + 7];
        *(float4*)(out + base)     = o0;
        *(float4*)(out + base + 4) = o1;
    }
}

// ---------------------------------------------------------------------------
// Launch: memset (cnt) + 3 kernels. Dispatch boundaries provide cross-XCD
// coherence (no grid.sync — round 3 showed it costs ~170 µs per sync here).
// ---------------------------------------------------------------------------
extern "C" void kernel_launch(void* const* d_in, const int* in_sizes, int n_in,
                              void* d_out, int out_size, void* d_ws, size_t ws_size,
                              hipStream_t stream) {
    const float* x    = (const float*)d_in[0];
    const int*   ei   = (const int*)  d_in[1];
    const float* W1_l = (const float*)d_in[2];
    const float* b1   = (const float*)d_in[3];
    const float* W1_r = (const float*)d_in[4];
    const float* W2_l = (const float*)d_in[5];
    const float* b2   = (const float*)d_in[6];
    const float* W2_r = (const float*)d_in[7];
    float* out = (float*)d_out;

    // ---- workspace layout (byte offsets, all 16 B-aligned) ----
    char* w = (char*)d_ws;
    int*      cnt   = (int*)     (w + 0);          //    40,000 B (reserve 64 KB)
    ushort_t* esrc2 = (ushort_t*)(w + 65536);      // 2,560,000 B
    ushort_t* xb    = (ushort_t*)(w + 2625536);    // 2,560,000 B
    ushort_t* Pb    = (ushort_t*)(w + 5185536);    // 2,560,000 B
    ushort_t* w1t   = (ushort_t*)(w + 7745536);    //   131,072 B
    ushort_t* w2tl  = (ushort_t*)(w + 7876608);    //    65,536 B
    ushort_t* w2tr  = (ushort_t*)(w + 7942144);    //    65,536 B
    float*    Rf    = (float*)   (w + 8007680);    // 5,120,000 B -> ends 13,127,680

    hipMemsetAsync(cnt, 0, N_NODES * sizeof(int), stream);

    prep_scatter<<<NB1, 256, 0, stream>>>(x, ei, W1_l, W1_r, W2_l, W2_r,
                                          xb, w1t, w2tl, w2tr, cnt, esrc2);
    gather_gemm<<<625, 512, 0, stream>>>(xb, cnt, esrc2, w1t, b1, w2tl, w2tr, Pb, Rf);
    gather_final<<<N_NODES, 64, 0, stream>>>(Pb, cnt, esrc2, Rf, b2, out);
}